// Round 4
// baseline (436.050 us; speedup 1.0000x reference)
//
#include <hip/hip_runtime.h>
#include <math.h>

#define T_STEPS 1024
#define BATCH   32
#define DIM     1024
#define NST     64
#define TBN     ((size_t)T_STEPS * BATCH * NST)   // 2M elements per projection

typedef __attribute__((ext_vector_type(8))) short bf16x8;
typedef __attribute__((ext_vector_type(4))) float f32x4;

#define NLOG2E (-1.44269504088896340736f)

// Pre-split bf16 hi/lo planes of k and q, written by the GEMM epilogue, consumed as
// ready-made MFMA fragments by the scan's per-chunk Gram/projection MFMAs (zero cvt there).
__device__ unsigned short g_khi[TBN];
__device__ unsigned short g_klo[TBN];
__device__ unsigned short g_qhi[TBN];
__device__ unsigned short g_qlo[TBN];

// ======================= Phase 1: hi/lo bf16 MFMA GEMM, global_load_lds 2-phase =======================
// Structure unchanged from r1-r3. Epilogue additions: k and q waves also store bf16 hi/lo
// planes (device globals); q fp32 plane no longer stored (nothing reads it);
// ax plane (nq==3) stored pre-scaled: -log2e*(ax + b_alpha).

__device__ __forceinline__ void gload16(const float* g, float* l)
{
    __builtin_amdgcn_global_load_lds(
        (const __attribute__((address_space(1))) unsigned int*)g,
        (__attribute__((address_space(3))) unsigned int*)l, 16, 0, 0);
}

__device__ __forceinline__ void cvt8(float4 v0, float4 v1, bf16x8& hi, bf16x8& lo)
{
    float f[8] = {v0.x, v0.y, v0.z, v0.w, v1.x, v1.y, v1.z, v1.w};
    bf16x8 h, l;
    #pragma unroll
    for (int i = 0; i < 8; i++) {
        unsigned b = __float_as_uint(f[i]);
        h[i] = (short)(b >> 16);                          // hi = truncate to bf16
        l[i] = (short)(__float_as_uint(f[i] - __uint_as_float(b & 0xffff0000u)) >> 16);
    }
    hi = h; lo = l;
}

__global__ __launch_bounds__(512, 1)
void proj_gemm_v2(const float* __restrict__ x,
                  const float* __restrict__ Wk,
                  const float* __restrict__ Wv,
                  const float* __restrict__ Wq,
                  const float* __restrict__ Wa,
                  const float* __restrict__ b_alpha,
                  float* __restrict__ ws)
{
    __shared__ float As[2][128][32];   // 32 KB
    __shared__ float Bs[2][256][32];   // 64 KB

    const int tid  = threadIdx.x;
    const int lane = tid & 63;
    const int w    = tid >> 6;          // wave 0..7
    const int m0   = blockIdx.x * 128;

    // staging: LDS pos p of row r holds GLOBAL granule p ^ (r&7)
    const int lrow  = lane >> 3;
    const int lgran = (lane & 7) ^ lrow;
    const float* ap0 = x + (size_t)(m0 + 16*w +     lrow) * DIM + lgran * 4;
    const float* ap1 = x + (size_t)(m0 + 16*w + 8 + lrow) * DIM + lgran * 4;
    const float* Wsrc = (w < 2) ? Wk : (w < 4) ? Wv : (w < 6) ? Wq : Wa;
    const float* bp0 = Wsrc + (size_t)((w & 1)*32 +  0 + lrow) * DIM + lgran * 4;
    const float* bp1 = Wsrc + (size_t)((w & 1)*32 +  8 + lrow) * DIM + lgran * 4;
    const float* bp2 = Wsrc + (size_t)((w & 1)*32 + 16 + lrow) * DIM + lgran * 4;
    const float* bp3 = Wsrc + (size_t)((w & 1)*32 + 24 + lrow) * DIM + lgran * 4;

    auto stage = [&](int kb, int buf) {
        const int ko = kb * 32;
        gload16(ap0 + ko, &As[buf][16*w     ][0]);
        gload16(ap1 + ko, &As[buf][16*w +  8][0]);
        gload16(bp0 + ko, &Bs[buf][32*w     ][0]);
        gload16(bp1 + ko, &Bs[buf][32*w +  8][0]);
        gload16(bp2 + ko, &Bs[buf][32*w + 16][0]);
        gload16(bp3 + ko, &Bs[buf][32*w + 24][0]);
    };

    const int fr = lane & 15;
    const int qi = lane >> 4;
    const int sx = fr & 7;
    const int mh = w >> 2;
    const int nq = w & 3;

    f32x4 acc[4][4];
    #pragma unroll
    for (int i = 0; i < 4; i++)
        #pragma unroll
        for (int j = 0; j < 4; j++)
            acc[i][j] = (f32x4)0.0f;

    stage(0, 0);
    __syncthreads();

    #pragma unroll 1
    for (int kb = 0; kb < 32; kb++) {
        const int buf = kb & 1;
        if (kb + 1 < 32) stage(kb + 1, buf ^ 1);

        bf16x8 ah[4], al[4], bh[4], bl[4];
        #pragma unroll
        for (int mt = 0; mt < 4; mt++) {
            const float* rp = &As[buf][mh*64 + mt*16 + fr][0];
            float4 v0 = *(const float4*)(rp + (((2*qi    ) ^ sx) * 4));
            float4 v1 = *(const float4*)(rp + (((2*qi + 1) ^ sx) * 4));
            cvt8(v0, v1, ah[mt], al[mt]);
        }
        #pragma unroll
        for (int nt = 0; nt < 4; nt++) {
            const float* rp = &Bs[buf][nq*64 + nt*16 + fr][0];
            float4 v0 = *(const float4*)(rp + (((2*qi    ) ^ sx) * 4));
            float4 v1 = *(const float4*)(rp + (((2*qi + 1) ^ sx) * 4));
            cvt8(v0, v1, bh[nt], bl[nt]);
        }
        #pragma unroll
        for (int mt = 0; mt < 4; mt++)
            #pragma unroll
            for (int nt = 0; nt < 4; nt++) {
                acc[mt][nt] = __builtin_amdgcn_mfma_f32_16x16x32_bf16(ah[mt], bh[nt], acc[mt][nt], 0, 0, 0);
                acc[mt][nt] = __builtin_amdgcn_mfma_f32_16x16x32_bf16(al[mt], bh[nt], acc[mt][nt], 0, 0, 0);
                acc[mt][nt] = __builtin_amdgcn_mfma_f32_16x16x32_bf16(ah[mt], bl[nt], acc[mt][nt], 0, 0, 0);
            }

        __syncthreads();
    }

    // epilogue
    float* outb = ws + (size_t)nq * TBN;
    const int r0 = qi * 4;
    float bav[4];
    #pragma unroll
    for (int nt = 0; nt < 4; nt++)
        bav[nt] = (nq == 3) ? b_alpha[nt*16 + fr] : 0.0f;
    const float scl = (nq == 3) ? NLOG2E : 1.0f;
    #pragma unroll
    for (int mt = 0; mt < 4; mt++)
        #pragma unroll
        for (int nt = 0; nt < 4; nt++)
            #pragma unroll
            for (int r = 0; r < 4; r++) {
                const float val = (acc[mt][nt][r] + bav[nt]) * scl;
                const size_t idx = (size_t)(m0 + mh*64 + mt*16 + r0 + r) * NST + nt*16 + fr;
                if (nq != 2)
                    outb[idx] = val;                    // k, v, ax fp32 planes
                if (nq == 0 || nq == 2) {               // k and q: bf16 hi/lo planes
                    const unsigned bits = __float_as_uint(val);
                    const unsigned short hi = (unsigned short)(bits >> 16);
                    const float lof = val - __uint_as_float(bits & 0xffff0000u);
                    const unsigned short lo = (unsigned short)(__float_as_uint(lof) >> 16);
                    if (nq == 0) { g_khi[idx] = hi; g_klo[idx] = lo; }
                    else         { g_qhi[idx] = hi; g_qlo[idx] = lo; }
                }
            }
}

// ======================= Phase 2: Gram-chunked scan, 1 row per wave =======================
// 2048 independent chains (32 b x 64 rows); wave = 1 row, 64 lanes = 64 state columns.
// Grid 512 blocks x 256 thr (4 rows of one batch / block) = 8 waves/CU = 2/SIMD: sibling
// wave hides chain/LDS latency (r3 post-mortem: 1 wave/SIMD exposed every stall).
// Per 16-step chunk, MFMA computes (hi/lo bf16 exact-split, fragments pre-split by GEMM):
//   G  = K.K^T   (16x16)      GQ = K.Q^T  (16x16)
//   R0 = S.K^T   (row vector) H0 = S.Q^T
// Then 16 steps of pure scalar/vector recurrence, NO reductions:
//   ret_t = readlane(R, s); alpha = sigmoid; b = (1-alpha)v
//   R <- alpha*R + b*G[s][j]; H <- alpha*H + b*GQ[s][j]; S <- alpha*S + b*k_t[col]
//   h_t = H[lane==s] (cndmask gather), outputs finished once per chunk.

#define SCH 16
#define NCH (T_STEPS / SCH)

__global__ __launch_bounds__(256, 2)
void scan_gram(const float* __restrict__ ws,
               const float* __restrict__ S0,
               const float* __restrict__ d_alpha,
               float* __restrict__ out)
{
    const float* kb_ = ws;             // k fp32 (for S update)
    const float* vb_ = ws + TBN;       // v fp32
    const float* ab_ = ws + 3 * TBN;   // pre-scaled -log2e*(ax+b_alpha)

    __shared__ float k_st[2][SCH][64];   // 8 KB  fp32 k, double-buffered
    __shared__ float va  [2][SCH][16];   // 2 KB  [0..3]=v rows, [4..7]=ax rows, 8..15 dup
    __shared__ float G_lds [SCH][16];    // 1 KB
    __shared__ float GQ_lds[SCH][16];    // 1 KB
    __shared__ float S_pvt[4][64];       // 1 KB  per-wave S transpose scratch

    const int tid  = threadIdx.x;
    const int lane = tid & 63;
    const int w    = tid >> 6;          // wave = row-in-group
    // XCD swizzle: all 16 row-groups of a batch share an XCD (kept from r1)
    const int bid  = blockIdx.x;
    const int b    = (bid & 7) * 4 + ((bid >> 3) & 3);
    const int rg   = bid >> 5;
    const int row  = rg * 4 + w;
    const int fr   = lane & 15;
    const int qi   = lane >> 4;

    const size_t stp = (size_t)BATCH * NST;   // 2048

    float S = S0[((size_t)b * NST + row) * NST + lane];   // one column per lane
    const float da_s = d_alpha[row] * NLOG2E;

    // fp32 staging (global_load_lds, linear dest): wave w covers steps 4w..4w+3
    const float* ksrc = kb_ + (size_t)(4*w + qi) * stp + (size_t)b * NST + fr * 4;
    // va: lane L -> [s=L>>2][slot=L&3]; slot0=v, slot1=ax, slots 2,3 harmless dups
    const float* vsrc = ((lane & 1) ? ab_ : vb_)
                      + (size_t)(lane >> 2) * stp + (size_t)b * NST + rg * 4;

    auto stage = [&](int ch, int buf) {
        gload16(ksrc + (size_t)ch * SCH * stp, &k_st[buf][4*w][0]);
        if (w == 0)
            gload16(vsrc + (size_t)ch * SCH * stp, &va[buf][0][0]);
    };

    stage(0, 0);
    __syncthreads();

    float* op = out + (size_t)b * NST + row;
    float R = 0.0f, H = 0.0f, hv = 0.0f;

    #pragma unroll 1
    for (int ch = 0; ch < NCH; ch++) {
        const int buf = ch & 1;
        if (ch + 1 < NCH) stage(ch + 1, buf ^ 1);

        // ---- K/Q bf16 fragments straight from pre-split global planes (L2-resident) ----
        // A-frag layout (matches verified GEMM): lane(fr,qi) holds row fr, k = kc*32+qi*8+j
        const size_t fb = (size_t)ch * SCH * stp + (size_t)fr * stp + (size_t)b * NST + qi * 8;
        const bf16x8 Kh0 = *(const bf16x8*)(g_khi + fb);
        const bf16x8 Kh1 = *(const bf16x8*)(g_khi + fb + 32);
        const bf16x8 Kl0 = *(const bf16x8*)(g_klo + fb);
        const bf16x8 Kl1 = *(const bf16x8*)(g_klo + fb + 32);
        const bf16x8 Qh0 = *(const bf16x8*)(g_qhi + fb);
        const bf16x8 Qh1 = *(const bf16x8*)(g_qhi + fb + 32);
        const bf16x8 Ql0 = *(const bf16x8*)(g_qlo + fb);
        const bf16x8 Ql1 = *(const bf16x8*)(g_qlo + fb + 32);

        // ---- S fragments via per-wave LDS transpose (all 16 A-rows = this wave's S row) ----
        S_pvt[w][lane] = S;
        bf16x8 Sh0, Sl0, Sh1, Sl1;
        {
            float4 s0 = *(const float4*)&S_pvt[w][qi * 8];
            float4 s1 = *(const float4*)&S_pvt[w][qi * 8 + 4];
            cvt8(s0, s1, Sh0, Sl0);
            float4 s2 = *(const float4*)&S_pvt[w][32 + qi * 8];
            float4 s3 = *(const float4*)&S_pvt[w][32 + qi * 8 + 4];
            cvt8(s2, s3, Sh1, Sl1);
        }

        // ---- Gram + projection MFMAs (hi/lo 3-term each) ----
        f32x4 aG = (f32x4)0.0f, aGQ = (f32x4)0.0f;
        f32x4 aR0 = (f32x4)0.0f, aR1 = (f32x4)0.0f;   // split accs: halve dep chain
        f32x4 aH0 = (f32x4)0.0f, aH1 = (f32x4)0.0f;

        aG = __builtin_amdgcn_mfma_f32_16x16x32_bf16(Kh0, Kh0, aG, 0, 0, 0);
        aG = __builtin_amdgcn_mfma_f32_16x16x32_bf16(Kh0, Kl0, aG, 0, 0, 0);
        aG = __builtin_amdgcn_mfma_f32_16x16x32_bf16(Kl0, Kh0, aG, 0, 0, 0);
        aG = __builtin_amdgcn_mfma_f32_16x16x32_bf16(Kh1, Kh1, aG, 0, 0, 0);
        aG = __builtin_amdgcn_mfma_f32_16x16x32_bf16(Kh1, Kl1, aG, 0, 0, 0);
        aG = __builtin_amdgcn_mfma_f32_16x16x32_bf16(Kl1, Kh1, aG, 0, 0, 0);

        aGQ = __builtin_amdgcn_mfma_f32_16x16x32_bf16(Kh0, Qh0, aGQ, 0, 0, 0);
        aGQ = __builtin_amdgcn_mfma_f32_16x16x32_bf16(Kh0, Ql0, aGQ, 0, 0, 0);
        aGQ = __builtin_amdgcn_mfma_f32_16x16x32_bf16(Kl0, Qh0, aGQ, 0, 0, 0);
        aGQ = __builtin_amdgcn_mfma_f32_16x16x32_bf16(Kh1, Qh1, aGQ, 0, 0, 0);
        aGQ = __builtin_amdgcn_mfma_f32_16x16x32_bf16(Kh1, Ql1, aGQ, 0, 0, 0);
        aGQ = __builtin_amdgcn_mfma_f32_16x16x32_bf16(Kl1, Qh1, aGQ, 0, 0, 0);

        aR0 = __builtin_amdgcn_mfma_f32_16x16x32_bf16(Sh0, Kh0, aR0, 0, 0, 0);
        aR0 = __builtin_amdgcn_mfma_f32_16x16x32_bf16(Sh0, Kl0, aR0, 0, 0, 0);
        aR0 = __builtin_amdgcn_mfma_f32_16x16x32_bf16(Sl0, Kh0, aR0, 0, 0, 0);
        aR1 = __builtin_amdgcn_mfma_f32_16x16x32_bf16(Sh1, Kh1, aR1, 0, 0, 0);
        aR1 = __builtin_amdgcn_mfma_f32_16x16x32_bf16(Sh1, Kl1, aR1, 0, 0, 0);
        aR1 = __builtin_amdgcn_mfma_f32_16x16x32_bf16(Sl1, Kh1, aR1, 0, 0, 0);

        aH0 = __builtin_amdgcn_mfma_f32_16x16x32_bf16(Sh0, Qh0, aH0, 0, 0, 0);
        aH0 = __builtin_amdgcn_mfma_f32_16x16x32_bf16(Sh0, Ql0, aH0, 0, 0, 0);
        aH0 = __builtin_amdgcn_mfma_f32_16x16x32_bf16(Sl0, Qh0, aH0, 0, 0, 0);
        aH1 = __builtin_amdgcn_mfma_f32_16x16x32_bf16(Sh1, Qh1, aH1, 0, 0, 0);
        aH1 = __builtin_amdgcn_mfma_f32_16x16x32_bf16(Sh1, Ql1, aH1, 0, 0, 0);
        aH1 = __builtin_amdgcn_mfma_f32_16x16x32_bf16(Sl1, Qh1, aH1, 0, 0, 0);

        // C-layout: col = lane&15, row = qi*4 + reg. Dump G/GQ (shared, benign identical
        // writes by the 4 waves); R0/H0: all C rows identical -> reg0 of every lane
        // already holds its column's value.
        #pragma unroll
        for (int r = 0; r < 4; r++) {
            G_lds [qi*4 + r][fr] = aG[r];
            GQ_lds[qi*4 + r][fr] = aGQ[r];
        }
        R = aR0[0] + aR1[0];
        H = aH0[0] + aH1[0];

        // ---- 16 steps: no reductions, chain = readlane->fma->exp2->rcp ----
        #pragma unroll
        for (int s = 0; s < SCH; s++) {
            const float kcv = k_st[buf][s][lane];
            const float Gv  = G_lds [s][fr];     // 4-way same-addr broadcast, conflict-free
            const float GQv = GQ_lds[s][fr];
            const float vv  = va[buf][s][w];
            const float aa  = va[buf][s][4 + w];

            const float ret   = __int_as_float(
                __builtin_amdgcn_readlane(__float_as_int(R), s));
            const float z     = fmaf(da_s, ret, aa);          // pre-scaled by -log2e
            const float e     = __builtin_amdgcn_exp2f(z);
            const float alpha = __builtin_amdgcn_rcpf(1.0f + e);
            const float bt    = (1.0f - alpha) * vv;

            R = fmaf(alpha, R, bt * Gv);
            H = fmaf(alpha, H, bt * GQv);
            S = fmaf(alpha, S, bt * kcv);

            hv = (lane == s) ? H : hv;            // h_t lands in lane s
        }

        // ---- chunk outputs: o = h * silu(h), one coalesced-ish masked store ----
        {
            const float zz = hv * NLOG2E;
            const float sg = __builtin_amdgcn_rcpf(1.0f + __builtin_amdgcn_exp2f(zz));
            const float o  = hv * hv * sg;
            if (lane < SCH)
                op[(size_t)(ch * SCH + lane) * stp] = o;
        }

        __syncthreads();   // staging drained; G_lds/k_st/va safe to rotate
    }

    // S_final: one column per lane, coalesced
    out[TBN + ((size_t)b * NST + row) * NST + lane] = S;
}

// ======================= launch =======================

extern "C" void kernel_launch(void* const* d_in, const int* in_sizes, int n_in,
                              void* d_out, int out_size, void* d_ws, size_t ws_size,
                              hipStream_t stream)
{
    const float* x  = (const float*)d_in[0];
    const float* S0 = (const float*)d_in[1];
    const float* Wk = (const float*)d_in[2];
    const float* Wv = (const float*)d_in[3];
    const float* Wq = (const float*)d_in[4];
    const float* Wa = (const float*)d_in[5];
    const float* da = (const float*)d_in[6];
    const float* ba = (const float*)d_in[7];
    float* out = (float*)d_out;
    float* ws  = (float*)d_ws;   // 4 x [T,B,N] fp32 = 32 MiB

    proj_gemm_v2<<<dim3((T_STEPS * BATCH) / 128), 512, 0, stream>>>(x, Wk, Wv, Wq, Wa, ba, ws);

    scan_gram<<<dim3(BATCH * 16), 256, 0, stream>>>(ws, S0, da, out);
}

// Round 5
// 382.212 us; speedup vs baseline: 1.1409x; 1.1409x over previous
//
#include <hip/hip_runtime.h>
#include <math.h>

#define T_STEPS 1024
#define BATCH   32
#define DIM     1024
#define NST     64
#define TBN     ((size_t)T_STEPS * BATCH * NST)   // 2M elements per projection

typedef __attribute__((ext_vector_type(8))) short bf16x8;
typedef __attribute__((ext_vector_type(4))) float f32x4;

#define NLOG2E (-1.44269504088896340736f)

// Pre-split bf16 hi/lo planes of k and q, written by the GEMM epilogue, staged chunk-ahead
// into LDS by the scan (global_load_lds), consumed as MFMA fragments there.
__device__ unsigned short g_khi[TBN];
__device__ unsigned short g_klo[TBN];
__device__ unsigned short g_qhi[TBN];
__device__ unsigned short g_qlo[TBN];

__device__ __forceinline__ void gload16(const void* g, void* l)
{
    __builtin_amdgcn_global_load_lds(
        (const __attribute__((address_space(1))) unsigned int*)g,
        (__attribute__((address_space(3))) unsigned int*)l, 16, 0, 0);
}

__device__ __forceinline__ void cvt8(float4 v0, float4 v1, bf16x8& hi, bf16x8& lo)
{
    float f[8] = {v0.x, v0.y, v0.z, v0.w, v1.x, v1.y, v1.z, v1.w};
    bf16x8 h, l;
    #pragma unroll
    for (int i = 0; i < 8; i++) {
        unsigned b = __float_as_uint(f[i]);
        h[i] = (short)(b >> 16);                          // hi = truncate to bf16
        l[i] = (short)(__float_as_uint(f[i] - __uint_as_float(b & 0xffff0000u)) >> 16);
    }
    hi = h; lo = l;
}

// ======================= Phase 1: hi/lo bf16 MFMA GEMM (unchanged from r4, passing) =======================

__global__ __launch_bounds__(512, 1)
void proj_gemm_v2(const float* __restrict__ x,
                  const float* __restrict__ Wk,
                  const float* __restrict__ Wv,
                  const float* __restrict__ Wq,
                  const float* __restrict__ Wa,
                  const float* __restrict__ b_alpha,
                  float* __restrict__ ws)
{
    __shared__ float As[2][128][32];   // 32 KB
    __shared__ float Bs[2][256][32];   // 64 KB

    const int tid  = threadIdx.x;
    const int lane = tid & 63;
    const int w    = tid >> 6;          // wave 0..7
    const int m0   = blockIdx.x * 128;

    // staging: LDS pos p of row r holds GLOBAL granule p ^ (r&7)
    const int lrow  = lane >> 3;
    const int lgran = (lane & 7) ^ lrow;
    const float* ap0 = x + (size_t)(m0 + 16*w +     lrow) * DIM + lgran * 4;
    const float* ap1 = x + (size_t)(m0 + 16*w + 8 + lrow) * DIM + lgran * 4;
    const float* Wsrc = (w < 2) ? Wk : (w < 4) ? Wv : (w < 6) ? Wq : Wa;
    const float* bp0 = Wsrc + (size_t)((w & 1)*32 +  0 + lrow) * DIM + lgran * 4;
    const float* bp1 = Wsrc + (size_t)((w & 1)*32 +  8 + lrow) * DIM + lgran * 4;
    const float* bp2 = Wsrc + (size_t)((w & 1)*32 + 16 + lrow) * DIM + lgran * 4;
    const float* bp3 = Wsrc + (size_t)((w & 1)*32 + 24 + lrow) * DIM + lgran * 4;

    auto stage = [&](int kb, int buf) {
        const int ko = kb * 32;
        gload16(ap0 + ko, &As[buf][16*w     ][0]);
        gload16(ap1 + ko, &As[buf][16*w +  8][0]);
        gload16(bp0 + ko, &Bs[buf][32*w     ][0]);
        gload16(bp1 + ko, &Bs[buf][32*w +  8][0]);
        gload16(bp2 + ko, &Bs[buf][32*w + 16][0]);
        gload16(bp3 + ko, &Bs[buf][32*w + 24][0]);
    };

    const int fr = lane & 15;
    const int qi = lane >> 4;
    const int sx = fr & 7;
    const int mh = w >> 2;
    const int nq = w & 3;

    f32x4 acc[4][4];
    #pragma unroll
    for (int i = 0; i < 4; i++)
        #pragma unroll
        for (int j = 0; j < 4; j++)
            acc[i][j] = (f32x4)0.0f;

    stage(0, 0);
    __syncthreads();

    #pragma unroll 1
    for (int kb = 0; kb < 32; kb++) {
        const int buf = kb & 1;
        if (kb + 1 < 32) stage(kb + 1, buf ^ 1);

        bf16x8 ah[4], al[4], bh[4], bl[4];
        #pragma unroll
        for (int mt = 0; mt < 4; mt++) {
            const float* rp = &As[buf][mh*64 + mt*16 + fr][0];
            float4 v0 = *(const float4*)(rp + (((2*qi    ) ^ sx) * 4));
            float4 v1 = *(const float4*)(rp + (((2*qi + 1) ^ sx) * 4));
            cvt8(v0, v1, ah[mt], al[mt]);
        }
        #pragma unroll
        for (int nt = 0; nt < 4; nt++) {
            const float* rp = &Bs[buf][nq*64 + nt*16 + fr][0];
            float4 v0 = *(const float4*)(rp + (((2*qi    ) ^ sx) * 4));
            float4 v1 = *(const float4*)(rp + (((2*qi + 1) ^ sx) * 4));
            cvt8(v0, v1, bh[nt], bl[nt]);
        }
        #pragma unroll
        for (int mt = 0; mt < 4; mt++)
            #pragma unroll
            for (int nt = 0; nt < 4; nt++) {
                acc[mt][nt] = __builtin_amdgcn_mfma_f32_16x16x32_bf16(ah[mt], bh[nt], acc[mt][nt], 0, 0, 0);
                acc[mt][nt] = __builtin_amdgcn_mfma_f32_16x16x32_bf16(al[mt], bh[nt], acc[mt][nt], 0, 0, 0);
                acc[mt][nt] = __builtin_amdgcn_mfma_f32_16x16x32_bf16(ah[mt], bl[nt], acc[mt][nt], 0, 0, 0);
            }

        __syncthreads();
    }

    // epilogue: fp32 k/v/ax planes (+ ax pre-scaled by -log2e, b_alpha folded); bf16 hi/lo k,q
    float* outb = ws + (size_t)nq * TBN;
    const int r0 = qi * 4;
    float bav[4];
    #pragma unroll
    for (int nt = 0; nt < 4; nt++)
        bav[nt] = (nq == 3) ? b_alpha[nt*16 + fr] : 0.0f;
    const float scl = (nq == 3) ? NLOG2E : 1.0f;
    #pragma unroll
    for (int mt = 0; mt < 4; mt++)
        #pragma unroll
        for (int nt = 0; nt < 4; nt++)
            #pragma unroll
            for (int r = 0; r < 4; r++) {
                const float val = (acc[mt][nt][r] + bav[nt]) * scl;
                const size_t idx = (size_t)(m0 + mh*64 + mt*16 + r0 + r) * NST + nt*16 + fr;
                if (nq != 2)
                    outb[idx] = val;
                if (nq == 0 || nq == 2) {
                    const unsigned bits = __float_as_uint(val);
                    const unsigned short hi = (unsigned short)(bits >> 16);
                    const float lof = val - __uint_as_float(bits & 0xffff0000u);
                    const unsigned short lo = (unsigned short)(__float_as_uint(lof) >> 16);
                    if (nq == 0) { g_khi[idx] = hi; g_klo[idx] = lo; }
                    else         { g_qhi[idx] = hi; g_qlo[idx] = lo; }
                }
            }
}

// ======================= Phase 2: Gram-chunked scan, fully LDS-pipelined =======================
// r4 structure (wave = 1 row, Gram tables kill all reductions) with the r4 stall removed:
//  - K/Q bf16 frag planes staged chunk-ahead via global_load_lds (fire-and-forget; no VGPR
//    liveness decision for the compiler to get wrong), XOR-swizzled source + swizzled
//    ds_read_b128 (both-sides rule) -> bank-conflict-free 128B-stride frag reads.
//  - Gram G/GQ split across waves (w0:G, w1:GQ) instead of 4x redundant.
//  - Two barriers per chunk, placed so NEITHER drains freshly-issued vmcnt:
//    A after Gram dump (only lgkm outstanding), stage issued after A, B ~800cy later.

#define SCH 16
#define NCH (T_STEPS / SCH)

__global__ __launch_bounds__(256, 2)
void scan_gram2(const float* __restrict__ ws,
                const float* __restrict__ S0,
                const float* __restrict__ d_alpha,
                float* __restrict__ out)
{
    const float* kb_ = ws;             // k fp32 (for S update)
    const float* vb_ = ws + TBN;       // v fp32
    const float* ab_ = ws + 3 * TBN;   // pre-scaled -log2e*(ax+b_alpha)

    __shared__ float k_st[2][SCH][64];            // 8 KB
    __shared__ float va  [2][SCH][16];            // 2 KB  [0..3]=v rows,[4..7]=ax rows,8..15 dup
    __shared__ float GG  [2][SCH][16][2];         // 4 KB  [s][j][{G,GQ}]
    __shared__ unsigned short KH[2][SCH][64];     // 4 KB each, 16 KB total
    __shared__ unsigned short KL[2][SCH][64];
    __shared__ unsigned short QH[2][SCH][64];
    __shared__ unsigned short QL[2][SCH][64];
    __shared__ float S_pvt[4][64];                // 1 KB

    const int tid  = threadIdx.x;
    const int lane = tid & 63;
    const int w    = tid >> 6;          // wave = row-in-group 0..3
    const int bid  = blockIdx.x;
    // XCD swizzle: all 16 row-groups of a batch share an XCD class
    const int b    = (bid & 7) * 4 + ((bid >> 3) & 3);
    const int rg   = bid >> 5;
    const int row  = rg * 4 + w;
    const int fr   = lane & 15;
    const int qi   = lane >> 4;

    const size_t stp = (size_t)BATCH * NST;   // 2048

    float S = S0[((size_t)b * NST + row) * NST + lane];   // one column per lane
    const float da_s = d_alpha[row] * NLOG2E;

    // ---- staging sources ----
    const float* ksrc = kb_ + (size_t)(4*w + qi) * stp + (size_t)b * NST + fr * 4;
    const float* vsrc = ((lane & 1) ? ab_ : vb_)
                      + (size_t)(lane >> 2) * stp + (size_t)b * NST + rg * 4;

    // frag planes: wave w stages plane w; source slot XOR-pre-swizzled (dest linear)
    const unsigned short* pl_g = (w == 0) ? g_khi : (w == 1) ? g_klo
                               : (w == 2) ? g_qhi : g_qlo;
    const int prow  = lane >> 3;                  // 0..7
    const int pgran = (lane & 7) ^ prow;          // swizzled source 16B-slot
    const unsigned short* psrc0 = pl_g + ((size_t)prow       * stp + (size_t)b * NST + pgran * 8);
    const unsigned short* psrc1 = pl_g + ((size_t)(8 + prow) * stp + (size_t)b * NST + pgran * 8);

    auto stage = [&](int ch, int buf) {
        const size_t koff = (size_t)ch * SCH * stp;
        gload16(ksrc + koff, &k_st[buf][4*w][0]);
        if (w == 0)
            gload16(vsrc + koff, &va[buf][0][0]);
        unsigned short* pdst = (w == 0) ? &KH[buf][0][0] : (w == 1) ? &KL[buf][0][0]
                             : (w == 2) ? &QH[buf][0][0] : &QL[buf][0][0];
        gload16(psrc0 + koff, pdst);
        gload16(psrc1 + koff, pdst + 8 * 64);
    };

    // read-side swizzle cols (ushort units): frag k-chunk 0 at slot qi, chunk 1 at slot qi^4
    const int c1 = (qi ^ (fr & 7)) * 8;
    const int c2 = c1 ^ 32;

    stage(0, 0);
    __syncthreads();

    float* op = out + (size_t)b * NST + row;
    float hv = 0.0f;

    #pragma unroll 1
    for (int ch = 0; ch < NCH; ch++) {
        const int buf = ch & 1;

        // ---- frag reads from swizzled LDS (bank-free b128) ----
        const bf16x8 Kh0 = *(const bf16x8*)&KH[buf][fr][c1];
        const bf16x8 Kh1 = *(const bf16x8*)&KH[buf][fr][c2];
        const bf16x8 Kl0 = *(const bf16x8*)&KL[buf][fr][c1];
        const bf16x8 Kl1 = *(const bf16x8*)&KL[buf][fr][c2];
        const bf16x8 Qh0 = *(const bf16x8*)&QH[buf][fr][c1];
        const bf16x8 Qh1 = *(const bf16x8*)&QH[buf][fr][c2];
        const bf16x8 Ql0 = *(const bf16x8*)&QL[buf][fr][c1];
        const bf16x8 Ql1 = *(const bf16x8*)&QL[buf][fr][c2];

        // ---- S broadcast + hi/lo split ----
        S_pvt[w][lane] = S;
        bf16x8 Sh0, Sl0, Sh1, Sl1;
        {
            float4 s0 = *(const float4*)&S_pvt[w][qi * 8];
            float4 s1 = *(const float4*)&S_pvt[w][qi * 8 + 4];
            cvt8(s0, s1, Sh0, Sl0);
            float4 s2 = *(const float4*)&S_pvt[w][32 + qi * 8];
            float4 s3 = *(const float4*)&S_pvt[w][32 + qi * 8 + 4];
            cvt8(s2, s3, Sh1, Sl1);
        }

        // ---- R0 = S.K^T, H0 = S.Q^T (all waves; hi/lo 3-term) ----
        f32x4 aR0 = (f32x4)0.0f, aR1 = (f32x4)0.0f;
        f32x4 aH0 = (f32x4)0.0f, aH1 = (f32x4)0.0f;
        aR0 = __builtin_amdgcn_mfma_f32_16x16x32_bf16(Sh0, Kh0, aR0, 0, 0, 0);
        aR0 = __builtin_amdgcn_mfma_f32_16x16x32_bf16(Sh0, Kl0, aR0, 0, 0, 0);
        aR0 = __builtin_amdgcn_mfma_f32_16x16x32_bf16(Sl0, Kh0, aR0, 0, 0, 0);
        aR1 = __builtin_amdgcn_mfma_f32_16x16x32_bf16(Sh1, Kh1, aR1, 0, 0, 0);
        aR1 = __builtin_amdgcn_mfma_f32_16x16x32_bf16(Sh1, Kl1, aR1, 0, 0, 0);
        aR1 = __builtin_amdgcn_mfma_f32_16x16x32_bf16(Sl1, Kh1, aR1, 0, 0, 0);
        aH0 = __builtin_amdgcn_mfma_f32_16x16x32_bf16(Sh0, Qh0, aH0, 0, 0, 0);
        aH0 = __builtin_amdgcn_mfma_f32_16x16x32_bf16(Sh0, Ql0, aH0, 0, 0, 0);
        aH0 = __builtin_amdgcn_mfma_f32_16x16x32_bf16(Sl0, Qh0, aH0, 0, 0, 0);
        aH1 = __builtin_amdgcn_mfma_f32_16x16x32_bf16(Sh1, Qh1, aH1, 0, 0, 0);
        aH1 = __builtin_amdgcn_mfma_f32_16x16x32_bf16(Sh1, Ql1, aH1, 0, 0, 0);
        aH1 = __builtin_amdgcn_mfma_f32_16x16x32_bf16(Sl1, Qh1, aH1, 0, 0, 0);
        float R = aR0[0] + aR1[0];
        float H = aH0[0] + aH1[0];

        // ---- Gram tables for THIS chunk, split across waves ----
        if (w == 0) {
            f32x4 aG = (f32x4)0.0f;
            aG = __builtin_amdgcn_mfma_f32_16x16x32_bf16(Kh0, Kh0, aG, 0, 0, 0);
            aG = __builtin_amdgcn_mfma_f32_16x16x32_bf16(Kh0, Kl0, aG, 0, 0, 0);
            aG = __builtin_amdgcn_mfma_f32_16x16x32_bf16(Kl0, Kh0, aG, 0, 0, 0);
            aG = __builtin_amdgcn_mfma_f32_16x16x32_bf16(Kh1, Kh1, aG, 0, 0, 0);
            aG = __builtin_amdgcn_mfma_f32_16x16x32_bf16(Kh1, Kl1, aG, 0, 0, 0);
            aG = __builtin_amdgcn_mfma_f32_16x16x32_bf16(Kl1, Kh1, aG, 0, 0, 0);
            #pragma unroll
            for (int r = 0; r < 4; r++) GG[buf][qi*4 + r][fr][0] = aG[r];
        } else if (w == 1) {
            f32x4 aQ = (f32x4)0.0f;
            aQ = __builtin_amdgcn_mfma_f32_16x16x32_bf16(Kh0, Qh0, aQ, 0, 0, 0);
            aQ = __builtin_amdgcn_mfma_f32_16x16x32_bf16(Kh0, Ql0, aQ, 0, 0, 0);
            aQ = __builtin_amdgcn_mfma_f32_16x16x32_bf16(Kl0, Qh0, aQ, 0, 0, 0);
            aQ = __builtin_amdgcn_mfma_f32_16x16x32_bf16(Kh1, Qh1, aQ, 0, 0, 0);
            aQ = __builtin_amdgcn_mfma_f32_16x16x32_bf16(Kh1, Ql1, aQ, 0, 0, 0);
            aQ = __builtin_amdgcn_mfma_f32_16x16x32_bf16(Kl1, Qh1, aQ, 0, 0, 0);
            #pragma unroll
            for (int r = 0; r < 4; r++) GG[buf][qi*4 + r][fr][1] = aQ[r];
        }

        __syncthreads();   // A: GG[buf] visible; only lgkm outstanding -> cheap drain

        if (ch + 1 < NCH) stage(ch + 1, buf ^ 1);   // loads fly under the step loop

        // ---- 16 steps: chain = readlane -> fma -> exp2 -> rcp; no reductions ----
        #pragma unroll
        for (int s = 0; s < SCH; s++) {
            const float  kcv = k_st[buf][s][lane];
            const float2 g2  = *(const float2*)&GG[buf][s][fr][0];
            const float  vv  = va[buf][s][w];
            const float  aa  = va[buf][s][4 + w];

            const float ret   = __int_as_float(
                __builtin_amdgcn_readlane(__float_as_int(R), s));
            const float z     = fmaf(da_s, ret, aa);          // pre-scaled by -log2e
            const float e     = __builtin_amdgcn_exp2f(z);
            const float alpha = __builtin_amdgcn_rcpf(1.0f + e);
            const float bt    = (1.0f - alpha) * vv;

            R = fmaf(alpha, R, bt * g2.x);
            H = fmaf(alpha, H, bt * g2.y);
            S = fmaf(alpha, S, bt * kcv);

            hv = (lane == s) ? H : hv;            // h_t lands in lane s
        }

        // ---- chunk outputs: o = h * silu(h) ----
        {
            const float sg = __builtin_amdgcn_rcpf(1.0f + __builtin_amdgcn_exp2f(hv * NLOG2E));
            const float o  = hv * hv * sg;
            if (lane < SCH)
                op[(size_t)(ch * SCH + lane) * stp] = o;
        }

        __syncthreads();   // B: step-loop LDS reads done; ch+1 stage loads (issued ~800cy ago) drained
    }

    // S_final: one column per lane, coalesced
    out[TBN + ((size_t)b * NST + row) * NST + lane] = S;
}

// ======================= launch =======================

extern "C" void kernel_launch(void* const* d_in, const int* in_sizes, int n_in,
                              void* d_out, int out_size, void* d_ws, size_t ws_size,
                              hipStream_t stream)
{
    const float* x  = (const float*)d_in[0];
    const float* S0 = (const float*)d_in[1];
    const float* Wk = (const float*)d_in[2];
    const float* Wv = (const float*)d_in[3];
    const float* Wq = (const float*)d_in[4];
    const float* Wa = (const float*)d_in[5];
    const float* da = (const float*)d_in[6];
    const float* ba = (const float*)d_in[7];
    float* out = (float*)d_out;
    float* ws  = (float*)d_ws;   // 4 x [T,B,N] fp32 = 32 MiB

    proj_gemm_v2<<<dim3((T_STEPS * BATCH) / 128), 512, 0, stream>>>(x, Wk, Wv, Wq, Wa, ba, ws);

    scan_gram2<<<dim3(BATCH * 16), 256, 0, stream>>>(ws, S0, da, out);
}

// Round 6
// 367.335 us; speedup vs baseline: 1.1871x; 1.0405x over previous
//
#include <hip/hip_runtime.h>
#include <math.h>

#define T_STEPS 1024
#define BATCH   32
#define DIM     1024
#define NST     64
#define TBN     ((size_t)T_STEPS * BATCH * NST)   // 2M elements per projection

typedef __attribute__((ext_vector_type(8))) short bf16x8;
typedef __attribute__((ext_vector_type(4))) float f32x4;

#define NLOG2E (-1.44269504088896340736f)
#define MFMA16(a, b, c) __builtin_amdgcn_mfma_f32_16x16x32_bf16(a, b, c, 0, 0, 0)

// Pre-split bf16 hi/lo planes of k and q (GEMM epilogue -> scan MFMA fragments).
__device__ unsigned short g_khi[TBN];
__device__ unsigned short g_klo[TBN];
__device__ unsigned short g_qhi[TBN];
__device__ unsigned short g_qlo[TBN];

__device__ __forceinline__ void gload16(const void* g, void* l)
{
    __builtin_amdgcn_global_load_lds(
        (const __attribute__((address_space(1))) unsigned int*)g,
        (__attribute__((address_space(3))) unsigned int*)l, 16, 0, 0);
}

__device__ __forceinline__ void cvt8(float4 v0, float4 v1, bf16x8& hi, bf16x8& lo)
{
    float f[8] = {v0.x, v0.y, v0.z, v0.w, v1.x, v1.y, v1.z, v1.w};
    bf16x8 h, l;
    #pragma unroll
    for (int i = 0; i < 8; i++) {
        unsigned b = __float_as_uint(f[i]);
        h[i] = (short)(b >> 16);                          // hi = truncate to bf16
        l[i] = (short)(__float_as_uint(f[i] - __uint_as_float(b & 0xffff0000u)) >> 16);
    }
    hi = h; lo = l;
}

// ======================= Phase 1: hi/lo bf16 MFMA GEMM, 128x128 tile, 2 blocks/CU =======================
// r5 post-mortem: the 128x256 / 96KB-LDS version ran 1 block/CU -> every K-step's
// barrier vmcnt(0) drain was fully exposed (no co-resident block). 128x128 / 64KB LDS
// gives 2 blocks/CU; one block's drain overlaps the other's compute. Per-wave frag /
// swizzle math identical to the verified r1-r5 kernel.

__global__ __launch_bounds__(256, 2)
void proj_gemm_v3(const float* __restrict__ x,
                  const float* __restrict__ Wk,
                  const float* __restrict__ Wv,
                  const float* __restrict__ Wq,
                  const float* __restrict__ Wa,
                  const float* __restrict__ b_alpha,
                  float* __restrict__ ws)
{
    __shared__ float As[2][128][32];   // 32 KB
    __shared__ float Bs[2][128][32];   // 32 KB

    const int tid  = threadIdx.x;
    const int lane = tid & 63;
    const int w    = tid >> 6;          // wave 0..3
    const int m0   = (blockIdx.x >> 1) * 128;
    const int nh   = blockIdx.x & 1;    // n-half: cols [128*nh, 128*nh+128) of fused 256

    // staging: LDS pos p of row r holds GLOBAL granule p ^ (r&7)
    const int lrow  = lane >> 3;
    const int lgran = (lane & 7) ^ lrow;
    const float* ap[4];
    #pragma unroll
    for (int i = 0; i < 4; i++)
        ap[i] = x + (size_t)(m0 + 32*w + 8*i + lrow) * DIM + lgran * 4;
    // B rows 32w..32w+32 of this block = fused cols nh*128 + 32w + .. -> one projection
    const int proj = nh * 2 + (w >> 1);
    const float* Wsrc = (proj == 0) ? Wk : (proj == 1) ? Wv : (proj == 2) ? Wq : Wa;
    const float* bp[4];
    #pragma unroll
    for (int i = 0; i < 4; i++)
        bp[i] = Wsrc + (size_t)((w & 1)*32 + 8*i + lrow) * DIM + lgran * 4;

    auto stage = [&](int kb, int buf) {
        const int ko = kb * 32;
        #pragma unroll
        for (int i = 0; i < 4; i++) {
            gload16(ap[i] + ko, &As[buf][32*w + 8*i][0]);
            gload16(bp[i] + ko, &Bs[buf][32*w + 8*i][0]);
        }
    };

    const int fr = lane & 15;
    const int qi = lane >> 4;
    const int sx = fr & 7;
    const int mh  = w >> 1;             // m-half 0..1
    const int nqh = w & 1;              // n-quarter within block

    f32x4 acc[4][4];
    #pragma unroll
    for (int i = 0; i < 4; i++)
        #pragma unroll
        for (int j = 0; j < 4; j++)
            acc[i][j] = (f32x4)0.0f;

    stage(0, 0);
    __syncthreads();

    #pragma unroll 1
    for (int kb = 0; kb < 32; kb++) {
        const int buf = kb & 1;
        if (kb + 1 < 32) stage(kb + 1, buf ^ 1);

        bf16x8 ah[4], al[4], bh[4], bl[4];
        #pragma unroll
        for (int mt = 0; mt < 4; mt++) {
            const float* rp = &As[buf][mh*64 + mt*16 + fr][0];
            float4 v0 = *(const float4*)(rp + (((2*qi    ) ^ sx) * 4));
            float4 v1 = *(const float4*)(rp + (((2*qi + 1) ^ sx) * 4));
            cvt8(v0, v1, ah[mt], al[mt]);
        }
        #pragma unroll
        for (int nt = 0; nt < 4; nt++) {
            const float* rp = &Bs[buf][nqh*64 + nt*16 + fr][0];
            float4 v0 = *(const float4*)(rp + (((2*qi    ) ^ sx) * 4));
            float4 v1 = *(const float4*)(rp + (((2*qi + 1) ^ sx) * 4));
            cvt8(v0, v1, bh[nt], bl[nt]);
        }
        #pragma unroll
        for (int mt = 0; mt < 4; mt++)
            #pragma unroll
            for (int nt = 0; nt < 4; nt++) {
                acc[mt][nt] = MFMA16(ah[mt], bh[nt], acc[mt][nt]);
                acc[mt][nt] = MFMA16(al[mt], bh[nt], acc[mt][nt]);
                acc[mt][nt] = MFMA16(ah[mt], bl[nt], acc[mt][nt]);
            }

        __syncthreads();
    }

    // epilogue: fp32 k/v/ax planes (ax pre-scaled by -log2e, b_alpha folded); bf16 hi/lo k,q
    const int nq = nh * 2 + nqh;        // projection this wave owns
    float* outb = ws + (size_t)nq * TBN;
    const int r0 = qi * 4;
    float bav[4];
    #pragma unroll
    for (int nt = 0; nt < 4; nt++)
        bav[nt] = (nq == 3) ? b_alpha[nt*16 + fr] : 0.0f;
    const float scl = (nq == 3) ? NLOG2E : 1.0f;
    #pragma unroll
    for (int mt = 0; mt < 4; mt++)
        #pragma unroll
        for (int nt = 0; nt < 4; nt++)
            #pragma unroll
            for (int r = 0; r < 4; r++) {
                const float val = (acc[mt][nt][r] + bav[nt]) * scl;
                const size_t idx = (size_t)(m0 + mh*64 + mt*16 + r0 + r) * NST + nt*16 + fr;
                if (nq != 2)
                    outb[idx] = val;
                if (nq == 0 || nq == 2) {
                    const unsigned bits = __float_as_uint(val);
                    const unsigned short hi = (unsigned short)(bits >> 16);
                    const float lof = val - __uint_as_float(bits & 0xffff0000u);
                    const unsigned short lo = (unsigned short)(__float_as_uint(lof) >> 16);
                    if (nq == 0) { g_khi[idx] = hi; g_klo[idx] = lo; }
                    else         { g_qhi[idx] = hi; g_qlo[idx] = lo; }
                }
            }
}

// ======================= Phase 2: Gram-chunked scan, 1 barrier/chunk, 5-op chain =======================
// r5 + two changes:
//  (1) Gram for chunk ch+1 computed DURING ch (frags triple-buffered, staged 2 ahead;
//      GG double-buffered) -> single end-of-chunk barrier. Race ledger:
//      GG[g^1] w(ch)->r(ch+1): 1 barrier.  GG[g] r(ch step loop) -> w(ch+1): 1 barrier.
//      KH[x] r(ch+1 head) -> w(stage in ch+2): 1 barrier.  k_st/va same pattern.
//      stage(ch+2) loads land before their first read (ch+1 head) via the issuing wave's
//      own vmcnt(0) drain at the end-of-ch barrier.
//  (2) Scalar-ret chain: ret_s = fma(a_{s-1}, rlR_s - vvG_s, vvG_s), with
//      rlR_s = readlane(R^{(s-2)}, s), vvG_s = vv_{s-1}*G[s-1][s] hoisted to step s-1
//      (off-chain). R/H/S updates deferred one step (apply a_{s-1} at step s).
//      Chain/step: fma -> fma -> exp2 -> add -> rcp (~36cy).

#define SCH 16
#define NCH (T_STEPS / SCH)

__global__ __launch_bounds__(256, 2)
void scan_gram3(const float* __restrict__ ws,
                const float* __restrict__ S0,
                const float* __restrict__ d_alpha,
                float* __restrict__ out)
{
    const float* kb_ = ws;             // k fp32 (for S update)
    const float* vb_ = ws + TBN;       // v fp32
    const float* ab_ = ws + 3 * TBN;   // pre-scaled -log2e*(ax+b_alpha)

    __shared__ float k_st[3][SCH][64];            // 12 KB
    __shared__ float va  [3][SCH][16];            // 3 KB
    __shared__ float GG  [2][SCH][16][2];         // 4 KB  [s][j][{G,GQ}]
    __shared__ unsigned short KH[3][SCH][64];     // 6 KB each, 24 KB total
    __shared__ unsigned short KL[3][SCH][64];
    __shared__ unsigned short QH[3][SCH][64];
    __shared__ unsigned short QL[3][SCH][64];
    __shared__ float S_pvt[4][64];                // 1 KB          => 44 KB total

    const int tid  = threadIdx.x;
    const int lane = tid & 63;
    const int w    = tid >> 6;          // wave = row-in-group 0..3
    const int bid  = blockIdx.x;
    // XCD swizzle: all 16 row-groups of a batch share an XCD class
    const int b    = (bid & 7) * 4 + ((bid >> 3) & 3);
    const int rg   = bid >> 5;
    const int row  = rg * 4 + w;
    const int fr   = lane & 15;
    const int qi   = lane >> 4;

    const size_t stp = (size_t)BATCH * NST;   // 2048

    float S = S0[((size_t)b * NST + row) * NST + lane];   // one column per lane
    const float da_s = d_alpha[row] * NLOG2E;

    // ---- staging sources ----
    const float* ksrc = kb_ + (size_t)(4*w + qi) * stp + (size_t)b * NST + fr * 4;
    const float* vsrc = ((lane & 1) ? ab_ : vb_)
                      + (size_t)(lane >> 2) * stp + (size_t)b * NST + rg * 4;

    const unsigned short* pl_g = (w == 0) ? g_khi : (w == 1) ? g_klo
                               : (w == 2) ? g_qhi : g_qlo;
    const int prow  = lane >> 3;
    const int pgran = (lane & 7) ^ prow;          // swizzled source 16B-slot
    const unsigned short* psrc0 = pl_g + ((size_t)prow       * stp + (size_t)b * NST + pgran * 8);
    const unsigned short* psrc1 = pl_g + ((size_t)(8 + prow) * stp + (size_t)b * NST + pgran * 8);

    auto stage = [&](int ch, int buf) {
        const size_t koff = (size_t)ch * SCH * stp;
        gload16(ksrc + koff, &k_st[buf][4*w][0]);
        if (w == 0)
            gload16(vsrc + koff, &va[buf][0][0]);
        unsigned short* pdst = (w == 0) ? &KH[buf][0][0] : (w == 1) ? &KL[buf][0][0]
                             : (w == 2) ? &QH[buf][0][0] : &QL[buf][0][0];
        gload16(psrc0 + koff, pdst);
        gload16(psrc1 + koff, pdst + 8 * 64);
    };

    // read-side swizzle cols (ushort units)
    const int c1 = (qi ^ (fr & 7)) * 8;
    const int c2 = c1 ^ 32;

    // Gram (w0: G = K.K^T, w1: GQ = K.Q^T) from frag buffer fbs into GG[gdst]
    auto gram = [&](int fbs, int gdst) {
        if (w == 0) {
            const bf16x8 kh0 = *(const bf16x8*)&KH[fbs][fr][c1];
            const bf16x8 kh1 = *(const bf16x8*)&KH[fbs][fr][c2];
            const bf16x8 kl0 = *(const bf16x8*)&KL[fbs][fr][c1];
            const bf16x8 kl1 = *(const bf16x8*)&KL[fbs][fr][c2];
            f32x4 aG = (f32x4)0.0f;
            aG = MFMA16(kh0, kh0, aG); aG = MFMA16(kh0, kl0, aG); aG = MFMA16(kl0, kh0, aG);
            aG = MFMA16(kh1, kh1, aG); aG = MFMA16(kh1, kl1, aG); aG = MFMA16(kl1, kh1, aG);
            #pragma unroll
            for (int r = 0; r < 4; r++) GG[gdst][qi*4 + r][fr][0] = aG[r];
        } else if (w == 1) {
            const bf16x8 kh0 = *(const bf16x8*)&KH[fbs][fr][c1];
            const bf16x8 kh1 = *(const bf16x8*)&KH[fbs][fr][c2];
            const bf16x8 kl0 = *(const bf16x8*)&KL[fbs][fr][c1];
            const bf16x8 kl1 = *(const bf16x8*)&KL[fbs][fr][c2];
            const bf16x8 qh0 = *(const bf16x8*)&QH[fbs][fr][c1];
            const bf16x8 qh1 = *(const bf16x8*)&QH[fbs][fr][c2];
            const bf16x8 ql0 = *(const bf16x8*)&QL[fbs][fr][c1];
            const bf16x8 ql1 = *(const bf16x8*)&QL[fbs][fr][c2];
            f32x4 aQ = (f32x4)0.0f;
            aQ = MFMA16(kh0, qh0, aQ); aQ = MFMA16(kh0, ql0, aQ); aQ = MFMA16(kl0, qh0, aQ);
            aQ = MFMA16(kh1, qh1, aQ); aQ = MFMA16(kh1, ql1, aQ); aQ = MFMA16(kl1, qh1, aQ);
            #pragma unroll
            for (int r = 0; r < 4; r++) GG[gdst][qi*4 + r][fr][1] = aQ[r];
        }
    };

    // prologue: chunks 0,1 staged; Gram(0) ready
    stage(0, 0);
    stage(1, 1);
    __syncthreads();          // chunks 0,1 resident
    gram(0, 0);
    __syncthreads();          // GG[0] visible (no fresh vmcnt at this barrier)

    float* op = out + (size_t)b * NST + row;

    #pragma unroll 1
    for (int ch = 0; ch < NCH; ch++) {
        const int fb = ch % 3;
        const int gb = ch & 1;

        // ---- R0/H0 for this chunk ----
        const bf16x8 Kh0 = *(const bf16x8*)&KH[fb][fr][c1];
        const bf16x8 Kh1 = *(const bf16x8*)&KH[fb][fr][c2];
        const bf16x8 Kl0 = *(const bf16x8*)&KL[fb][fr][c1];
        const bf16x8 Kl1 = *(const bf16x8*)&KL[fb][fr][c2];
        const bf16x8 Qh0 = *(const bf16x8*)&QH[fb][fr][c1];
        const bf16x8 Qh1 = *(const bf16x8*)&QH[fb][fr][c2];
        const bf16x8 Ql0 = *(const bf16x8*)&QL[fb][fr][c1];
        const bf16x8 Ql1 = *(const bf16x8*)&QL[fb][fr][c2];

        S_pvt[w][lane] = S;
        bf16x8 Sh0, Sl0, Sh1, Sl1;
        {
            float4 s0 = *(const float4*)&S_pvt[w][qi * 8];
            float4 s1 = *(const float4*)&S_pvt[w][qi * 8 + 4];
            cvt8(s0, s1, Sh0, Sl0);
            float4 s2 = *(const float4*)&S_pvt[w][32 + qi * 8];
            float4 s3 = *(const float4*)&S_pvt[w][32 + qi * 8 + 4];
            cvt8(s2, s3, Sh1, Sl1);
        }

        f32x4 aR0 = (f32x4)0.0f, aR1 = (f32x4)0.0f;
        f32x4 aH0 = (f32x4)0.0f, aH1 = (f32x4)0.0f;
        aR0 = MFMA16(Sh0, Kh0, aR0); aR0 = MFMA16(Sh0, Kl0, aR0); aR0 = MFMA16(Sl0, Kh0, aR0);
        aR1 = MFMA16(Sh1, Kh1, aR1); aR1 = MFMA16(Sh1, Kl1, aR1); aR1 = MFMA16(Sl1, Kh1, aR1);
        aH0 = MFMA16(Sh0, Qh0, aH0); aH0 = MFMA16(Sh0, Ql0, aH0); aH0 = MFMA16(Sl0, Qh0, aH0);
        aH1 = MFMA16(Sh1, Qh1, aH1); aH1 = MFMA16(Sh1, Ql1, aH1); aH1 = MFMA16(Sl1, Qh1, aH1);
        float R = aR0[0] + aR1[0];
        float H = aH0[0] + aH1[0];

        // ---- Gram for NEXT chunk (w0/w1; w2/w3 fall straight through to the step loop) ----
        if (ch + 1 < NCH) gram((ch + 1) % 3, gb ^ 1);

        // ---- stage chunk ch+2 (lands before its first read: end-of-chunk barrier drains) ----
        if (ch + 2 < NCH) stage(ch + 2, (ch + 2) % 3);

        // ---- 16 steps; chain = fma -> fma -> exp2 -> add -> rcp ----
        float alpha_p = 1.0f, vv_p = 0.0f;
        float g_p = 0.0f, gq_p = 0.0f, kc_p = 0.0f;
        float vvG  = 0.0f;
        float diff = __int_as_float(__builtin_amdgcn_readlane(__float_as_int(R), 0));
        float hv   = 0.0f;

        #pragma unroll
        for (int s = 0; s < SCH; s++) {
            // operands (static LDS indices)
            const float2 g2  = *(const float2*)&GG[gb][s][fr][0];
            const float  kcv = k_st[fb][s][lane];
            const float  vv  = va[fb][s][w];
            const float  aa  = va[fb][s][4 + w];

            // deferred updates of step s-1 (alpha_p known since last iter; off today's chain)
            const float bt_p = (1.0f - alpha_p) * vv_p;
            R = fmaf(alpha_p, R, bt_p * g_p);
            H = fmaf(alpha_p, H, bt_p * gq_p);
            S = fmaf(alpha_p, S, bt_p * kc_p);
            if (s >= 1) hv = (lane == s - 1) ? H : hv;

            // hoisted scalars for step s+1 (off-chain)
            const float rlR = __int_as_float(__builtin_amdgcn_readlane(__float_as_int(R), s + 1));
            const float rlG = __int_as_float(__builtin_amdgcn_readlane(__float_as_int(g2.x), s + 1));

            // --- chain ---
            const float ret   = fmaf(alpha_p, diff, vvG);
            const float z     = fmaf(da_s, ret, aa);          // pre-scaled by -log2e
            const float e     = __builtin_amdgcn_exp2f(z);
            const float alpha = __builtin_amdgcn_rcpf(1.0f + e);

            // next-step chain inputs
            const float vvG_n  = vv * rlG;
            const float diff_n = rlR - vvG_n;

            // rotate
            alpha_p = alpha; vv_p = vv;
            g_p = g2.x; gq_p = g2.y; kc_p = kcv;
            vvG = vvG_n; diff = diff_n;
        }

        // final deferred update (step 15) — R no longer needed
        {
            const float bt_p = (1.0f - alpha_p) * vv_p;
            H = fmaf(alpha_p, H, bt_p * gq_p);
            S = fmaf(alpha_p, S, bt_p * kc_p);
            hv = (lane == SCH - 1) ? H : hv;
        }

        // ---- chunk outputs: o = h * silu(h) ----
        {
            const float sg = __builtin_amdgcn_rcpf(1.0f + __builtin_amdgcn_exp2f(hv * NLOG2E));
            const float o  = hv * hv * sg;
            if (lane < SCH)
                op[(size_t)(ch * SCH + lane) * stp] = o;
        }

        __syncthreads();   // single barrier: publishes GG[gb^1], retires this chunk's LDS reads
    }

    // S_final: one column per lane, coalesced
    out[TBN + ((size_t)b * NST + row) * NST + lane] = S;
}

// ======================= launch =======================

extern "C" void kernel_launch(void* const* d_in, const int* in_sizes, int n_in,
                              void* d_out, int out_size, void* d_ws, size_t ws_size,
                              hipStream_t stream)
{
    const float* x  = (const float*)d_in[0];
    const float* S0 = (const float*)d_in[1];
    const float* Wk = (const float*)d_in[2];
    const float* Wv = (const float*)d_in[3];
    const float* Wq = (const float*)d_in[4];
    const float* Wa = (const float*)d_in[5];
    const float* da = (const float*)d_in[6];
    const float* ba = (const float*)d_in[7];
    float* out = (float*)d_out;
    float* ws  = (float*)d_ws;   // 4 x [T,B,N] fp32 = 32 MiB

    proj_gemm_v3<<<dim3((T_STEPS * BATCH) / 128 * 2), 256, 0, stream>>>(x, Wk, Wv, Wq, Wa, ba, ws);

    scan_gram3<<<dim3(BATCH * 16), 256, 0, stream>>>(ws, S0, da, out);
}

// Round 7
// 356.199 us; speedup vs baseline: 1.2242x; 1.0313x over previous
//
#include <hip/hip_runtime.h>
#include <hip/hip_bf16.h>
#include <math.h>

#define T_STEPS 1024
#define BATCH   32
#define DIM     1024
#define NST     64
#define TBN     ((size_t)T_STEPS * BATCH * NST)   // 2M elements per projection

typedef __attribute__((ext_vector_type(8))) short bf16x8;
typedef __attribute__((ext_vector_type(4))) float f32x4;

#define NLOG2E (-1.44269504088896340736f)
#define MFMA16(a, b, c) __builtin_amdgcn_mfma_f32_16x16x32_bf16(a, b, c, 0, 0, 0)

// Pre-split bf16 hi/lo planes of k and q (GEMM epilogue -> scan MFMA fragments).
__device__ unsigned short g_khi[TBN];
__device__ unsigned short g_klo[TBN];
__device__ unsigned short g_qhi[TBN];
__device__ unsigned short g_qlo[TBN];

__device__ __forceinline__ void gload16(const void* g, void* l)
{
    __builtin_amdgcn_global_load_lds(
        (const __attribute__((address_space(1))) unsigned int*)g,
        (__attribute__((address_space(3))) unsigned int*)l, 16, 0, 0);
}

// RNE hi/lo split via HW bf16 cvt (compiler pairs casts into v_cvt_pk_bf16_f32).
// x = hi + lo with |lo| <= 2^-9|x|, lo itself bf16 (residual ~2^-17|x| dropped).
__device__ __forceinline__ void split1_rne(float v, unsigned short& hi, unsigned short& lo)
{
    __hip_bfloat16 hb = __float2bfloat16(v);
    unsigned short hraw; __builtin_memcpy(&hraw, &hb, 2);
    float hf = __bfloat162float(hb);
    __hip_bfloat16 lb = __float2bfloat16(v - hf);
    unsigned short lraw; __builtin_memcpy(&lraw, &lb, 2);
    hi = hraw; lo = lraw;
}

__device__ __forceinline__ void cvt8(float4 v0, float4 v1, bf16x8& hi, bf16x8& lo)
{
    float f[8] = {v0.x, v0.y, v0.z, v0.w, v1.x, v1.y, v1.z, v1.w};
    bf16x8 h, l;
    #pragma unroll
    for (int i = 0; i < 8; i++) {
        unsigned short hr, lr;
        split1_rne(f[i], hr, lr);
        h[i] = (short)hr; l[i] = (short)lr;
    }
    hi = h; lo = l;
}

// ======================= Phase 1: hi/lo bf16 MFMA GEMM, 128x128 tile, 2 blocks/CU =======================
// r6 structure (measured -35us vs 128x256/1blk). r7 change: truncate split -> RNE split
// (HW cvt path), cutting the VALU-bound inner loop's split cost ~2.4x.

__global__ __launch_bounds__(256, 2)
void proj_gemm_v3(const float* __restrict__ x,
                  const float* __restrict__ Wk,
                  const float* __restrict__ Wv,
                  const float* __restrict__ Wq,
                  const float* __restrict__ Wa,
                  const float* __restrict__ b_alpha,
                  float* __restrict__ ws)
{
    __shared__ float As[2][128][32];   // 32 KB
    __shared__ float Bs[2][128][32];   // 32 KB

    const int tid  = threadIdx.x;
    const int lane = tid & 63;
    const int w    = tid >> 6;          // wave 0..3
    const int m0   = (blockIdx.x >> 1) * 128;
    const int nh   = blockIdx.x & 1;    // n-half: cols [128*nh, 128*nh+128) of fused 256

    // staging: LDS pos p of row r holds GLOBAL granule p ^ (r&7)
    const int lrow  = lane >> 3;
    const int lgran = (lane & 7) ^ lrow;
    const float* ap[4];
    #pragma unroll
    for (int i = 0; i < 4; i++)
        ap[i] = x + (size_t)(m0 + 32*w + 8*i + lrow) * DIM + lgran * 4;
    const int proj = nh * 2 + (w >> 1);
    const float* Wsrc = (proj == 0) ? Wk : (proj == 1) ? Wv : (proj == 2) ? Wq : Wa;
    const float* bp[4];
    #pragma unroll
    for (int i = 0; i < 4; i++)
        bp[i] = Wsrc + (size_t)((w & 1)*32 + 8*i + lrow) * DIM + lgran * 4;

    auto stage = [&](int kb, int buf) {
        const int ko = kb * 32;
        #pragma unroll
        for (int i = 0; i < 4; i++) {
            gload16(ap[i] + ko, &As[buf][32*w + 8*i][0]);
            gload16(bp[i] + ko, &Bs[buf][32*w + 8*i][0]);
        }
    };

    const int fr = lane & 15;
    const int qi = lane >> 4;
    const int sx = fr & 7;
    const int mh  = w >> 1;             // m-half 0..1
    const int nqh = w & 1;              // n-quarter within block

    f32x4 acc[4][4];
    #pragma unroll
    for (int i = 0; i < 4; i++)
        #pragma unroll
        for (int j = 0; j < 4; j++)
            acc[i][j] = (f32x4)0.0f;

    stage(0, 0);
    __syncthreads();

    #pragma unroll 1
    for (int kb = 0; kb < 32; kb++) {
        const int buf = kb & 1;
        if (kb + 1 < 32) stage(kb + 1, buf ^ 1);

        bf16x8 ah[4], al[4], bh[4], bl[4];
        #pragma unroll
        for (int mt = 0; mt < 4; mt++) {
            const float* rp = &As[buf][mh*64 + mt*16 + fr][0];
            float4 v0 = *(const float4*)(rp + (((2*qi    ) ^ sx) * 4));
            float4 v1 = *(const float4*)(rp + (((2*qi + 1) ^ sx) * 4));
            cvt8(v0, v1, ah[mt], al[mt]);
        }
        #pragma unroll
        for (int nt = 0; nt < 4; nt++) {
            const float* rp = &Bs[buf][nqh*64 + nt*16 + fr][0];
            float4 v0 = *(const float4*)(rp + (((2*qi    ) ^ sx) * 4));
            float4 v1 = *(const float4*)(rp + (((2*qi + 1) ^ sx) * 4));
            cvt8(v0, v1, bh[nt], bl[nt]);
        }
        #pragma unroll
        for (int mt = 0; mt < 4; mt++)
            #pragma unroll
            for (int nt = 0; nt < 4; nt++) {
                acc[mt][nt] = MFMA16(ah[mt], bh[nt], acc[mt][nt]);
                acc[mt][nt] = MFMA16(al[mt], bh[nt], acc[mt][nt]);
                acc[mt][nt] = MFMA16(ah[mt], bl[nt], acc[mt][nt]);
            }

        __syncthreads();
    }

    // epilogue: fp32 k/v/ax planes (ax pre-scaled by -log2e, b_alpha folded); bf16 hi/lo k,q
    const int nq = nh * 2 + nqh;        // projection this wave owns
    float* outb = ws + (size_t)nq * TBN;
    const int r0 = qi * 4;
    float bav[4];
    #pragma unroll
    for (int nt = 0; nt < 4; nt++)
        bav[nt] = (nq == 3) ? b_alpha[nt*16 + fr] : 0.0f;
    const float scl = (nq == 3) ? NLOG2E : 1.0f;
    #pragma unroll
    for (int mt = 0; mt < 4; mt++)
        #pragma unroll
        for (int nt = 0; nt < 4; nt++)
            #pragma unroll
            for (int r = 0; r < 4; r++) {
                const float val = (acc[mt][nt][r] + bav[nt]) * scl;
                const size_t idx = (size_t)(m0 + mh*64 + mt*16 + r0 + r) * NST + nt*16 + fr;
                if (nq != 2)
                    outb[idx] = val;
                if (nq == 0 || nq == 2) {
                    unsigned short hr, lr;
                    split1_rne(val, hr, lr);
                    if (nq == 0) { g_khi[idx] = hr; g_klo[idx] = lr; }
                    else         { g_qhi[idx] = hr; g_qlo[idx] = lr; }
                }
            }
}

// ======================= Phase 2: Gram-chunked scan (r5 structure, measured 131us) =======================
// Reverted from r6's 5-op-chain variant (+20us regression: hand-rotation movs + 2nd readlane).
// wave = 1 row, 64 lanes = 64 state cols; K/Q frag planes staged chunk-ahead via
// global_load_lds (XOR-swizzled source + swizzled b128 reads); Gram G/GQ split w0/w1;
// step loop: readlane(R,s) -> sigmoid chain -> R/H/S fma updates, no reductions.

#define SCH 16
#define NCH (T_STEPS / SCH)

__global__ __launch_bounds__(256, 2)
void scan_gram2(const float* __restrict__ ws,
                const float* __restrict__ S0,
                const float* __restrict__ d_alpha,
                float* __restrict__ out)
{
    const float* kb_ = ws;             // k fp32 (for S update)
    const float* vb_ = ws + TBN;       // v fp32
    const float* ab_ = ws + 3 * TBN;   // pre-scaled -log2e*(ax+b_alpha)

    __shared__ float k_st[2][SCH][64];            // 8 KB
    __shared__ float va  [2][SCH][16];            // 2 KB
    __shared__ float GG  [2][SCH][16][2];         // 4 KB  [s][j][{G,GQ}]
    __shared__ unsigned short KH[2][SCH][64];     // 4 KB each, 16 KB total
    __shared__ unsigned short KL[2][SCH][64];
    __shared__ unsigned short QH[2][SCH][64];
    __shared__ unsigned short QL[2][SCH][64];
    __shared__ float S_pvt[4][64];                // 1 KB

    const int tid  = threadIdx.x;
    const int lane = tid & 63;
    const int w    = tid >> 6;          // wave = row-in-group 0..3
    const int bid  = blockIdx.x;
    // XCD swizzle: all 16 row-groups of a batch share an XCD class
    const int b    = (bid & 7) * 4 + ((bid >> 3) & 3);
    const int rg   = bid >> 5;
    const int row  = rg * 4 + w;
    const int fr   = lane & 15;
    const int qi   = lane >> 4;

    const size_t stp = (size_t)BATCH * NST;   // 2048

    float S = S0[((size_t)b * NST + row) * NST + lane];   // one column per lane
    const float da_s = d_alpha[row] * NLOG2E;

    // ---- staging sources ----
    const float* ksrc = kb_ + (size_t)(4*w + qi) * stp + (size_t)b * NST + fr * 4;
    const float* vsrc = ((lane & 1) ? ab_ : vb_)
                      + (size_t)(lane >> 2) * stp + (size_t)b * NST + rg * 4;

    const unsigned short* pl_g = (w == 0) ? g_khi : (w == 1) ? g_klo
                               : (w == 2) ? g_qhi : g_qlo;
    const int prow  = lane >> 3;
    const int pgran = (lane & 7) ^ prow;          // swizzled source 16B-slot
    const unsigned short* psrc0 = pl_g + ((size_t)prow       * stp + (size_t)b * NST + pgran * 8);
    const unsigned short* psrc1 = pl_g + ((size_t)(8 + prow) * stp + (size_t)b * NST + pgran * 8);

    auto stage = [&](int ch, int buf) {
        const size_t koff = (size_t)ch * SCH * stp;
        gload16(ksrc + koff, &k_st[buf][4*w][0]);
        if (w == 0)
            gload16(vsrc + koff, &va[buf][0][0]);
        unsigned short* pdst = (w == 0) ? &KH[buf][0][0] : (w == 1) ? &KL[buf][0][0]
                             : (w == 2) ? &QH[buf][0][0] : &QL[buf][0][0];
        gload16(psrc0 + koff, pdst);
        gload16(psrc1 + koff, pdst + 8 * 64);
    };

    // read-side swizzle cols (ushort units)
    const int c1 = (qi ^ (fr & 7)) * 8;
    const int c2 = c1 ^ 32;

    stage(0, 0);
    __syncthreads();

    float* op = out + (size_t)b * NST + row;
    float hv = 0.0f;

    #pragma unroll 1
    for (int ch = 0; ch < NCH; ch++) {
        const int buf = ch & 1;

        // ---- frag reads from swizzled LDS (bank-free b128) ----
        const bf16x8 Kh0 = *(const bf16x8*)&KH[buf][fr][c1];
        const bf16x8 Kh1 = *(const bf16x8*)&KH[buf][fr][c2];
        const bf16x8 Kl0 = *(const bf16x8*)&KL[buf][fr][c1];
        const bf16x8 Kl1 = *(const bf16x8*)&KL[buf][fr][c2];
        const bf16x8 Qh0 = *(const bf16x8*)&QH[buf][fr][c1];
        const bf16x8 Qh1 = *(const bf16x8*)&QH[buf][fr][c2];
        const bf16x8 Ql0 = *(const bf16x8*)&QL[buf][fr][c1];
        const bf16x8 Ql1 = *(const bf16x8*)&QL[buf][fr][c2];

        // ---- S broadcast + hi/lo split (RNE) ----
        S_pvt[w][lane] = S;
        bf16x8 Sh0, Sl0, Sh1, Sl1;
        {
            float4 s0 = *(const float4*)&S_pvt[w][qi * 8];
            float4 s1 = *(const float4*)&S_pvt[w][qi * 8 + 4];
            cvt8(s0, s1, Sh0, Sl0);
            float4 s2 = *(const float4*)&S_pvt[w][32 + qi * 8];
            float4 s3 = *(const float4*)&S_pvt[w][32 + qi * 8 + 4];
            cvt8(s2, s3, Sh1, Sl1);
        }

        // ---- R0 = S.K^T, H0 = S.Q^T (all waves; hi/lo 3-term) ----
        f32x4 aR0 = (f32x4)0.0f, aR1 = (f32x4)0.0f;
        f32x4 aH0 = (f32x4)0.0f, aH1 = (f32x4)0.0f;
        aR0 = MFMA16(Sh0, Kh0, aR0); aR0 = MFMA16(Sh0, Kl0, aR0); aR0 = MFMA16(Sl0, Kh0, aR0);
        aR1 = MFMA16(Sh1, Kh1, aR1); aR1 = MFMA16(Sh1, Kl1, aR1); aR1 = MFMA16(Sl1, Kh1, aR1);
        aH0 = MFMA16(Sh0, Qh0, aH0); aH0 = MFMA16(Sh0, Ql0, aH0); aH0 = MFMA16(Sl0, Qh0, aH0);
        aH1 = MFMA16(Sh1, Qh1, aH1); aH1 = MFMA16(Sh1, Ql1, aH1); aH1 = MFMA16(Sl1, Qh1, aH1);
        float R = aR0[0] + aR1[0];
        float H = aH0[0] + aH1[0];

        // ---- Gram tables for THIS chunk, split across waves ----
        if (w == 0) {
            f32x4 aG = (f32x4)0.0f;
            aG = MFMA16(Kh0, Kh0, aG); aG = MFMA16(Kh0, Kl0, aG); aG = MFMA16(Kl0, Kh0, aG);
            aG = MFMA16(Kh1, Kh1, aG); aG = MFMA16(Kh1, Kl1, aG); aG = MFMA16(Kl1, Kh1, aG);
            #pragma unroll
            for (int r = 0; r < 4; r++) GG[buf][qi*4 + r][fr][0] = aG[r];
        } else if (w == 1) {
            f32x4 aQ = (f32x4)0.0f;
            aQ = MFMA16(Kh0, Qh0, aQ); aQ = MFMA16(Kh0, Ql0, aQ); aQ = MFMA16(Kl0, Qh0, aQ);
            aQ = MFMA16(Kh1, Qh1, aQ); aQ = MFMA16(Kh1, Ql1, aQ); aQ = MFMA16(Kl1, Qh1, aQ);
            #pragma unroll
            for (int r = 0; r < 4; r++) GG[buf][qi*4 + r][fr][1] = aQ[r];
        }

        __syncthreads();   // A: GG[buf] visible; only lgkm outstanding -> cheap drain

        if (ch + 1 < NCH) stage(ch + 1, buf ^ 1);   // loads fly under the step loop

        // ---- 16 steps: chain = readlane -> fma -> exp2 -> rcp; no reductions ----
        #pragma unroll
        for (int s = 0; s < SCH; s++) {
            const float  kcv = k_st[buf][s][lane];
            const float2 g2  = *(const float2*)&GG[buf][s][fr][0];
            const float  vv  = va[buf][s][w];
            const float  aa  = va[buf][s][4 + w];

            const float ret   = __int_as_float(
                __builtin_amdgcn_readlane(__float_as_int(R), s));
            const float z     = fmaf(da_s, ret, aa);          // pre-scaled by -log2e
            const float e     = __builtin_amdgcn_exp2f(z);
            const float alpha = __builtin_amdgcn_rcpf(1.0f + e);
            const float bt    = (1.0f - alpha) * vv;

            R = fmaf(alpha, R, bt * g2.x);
            H = fmaf(alpha, H, bt * g2.y);
            S = fmaf(alpha, S, bt * kcv);

            hv = (lane == s) ? H : hv;            // h_t lands in lane s
        }

        // ---- chunk outputs: o = h * silu(h) ----
        {
            const float sg = __builtin_amdgcn_rcpf(1.0f + __builtin_amdgcn_exp2f(hv * NLOG2E));
            const float o  = hv * hv * sg;
            if (lane < SCH)
                op[(size_t)(ch * SCH + lane) * stp] = o;
        }

        __syncthreads();   // B: step-loop LDS reads done; next-chunk stage loads drained
    }

    // S_final: one column per lane, coalesced
    out[TBN + ((size_t)b * NST + row) * NST + lane] = S;
}

// ======================= launch =======================

extern "C" void kernel_launch(void* const* d_in, const int* in_sizes, int n_in,
                              void* d_out, int out_size, void* d_ws, size_t ws_size,
                              hipStream_t stream)
{
    const float* x  = (const float*)d_in[0];
    const float* S0 = (const float*)d_in[1];
    const float* Wk = (const float*)d_in[2];
    const float* Wv = (const float*)d_in[3];
    const float* Wq = (const float*)d_in[4];
    const float* Wa = (const float*)d_in[5];
    const float* da = (const float*)d_in[6];
    const float* ba = (const float*)d_in[7];
    float* out = (float*)d_out;
    float* ws  = (float*)d_ws;   // 4 x [T,B,N] fp32 = 32 MiB

    proj_gemm_v3<<<dim3((T_STEPS * BATCH) / 128 * 2), 256, 0, stream>>>(x, Wk, Wv, Wq, Wa, ba, ws);

    scan_gram2<<<dim3(BATCH * 16), 256, 0, stream>>>(ws, S0, da, out);
}

// Round 8
// 353.801 us; speedup vs baseline: 1.2325x; 1.0068x over previous
//
#include <hip/hip_runtime.h>
#include <hip/hip_bf16.h>
#include <math.h>

#define T_STEPS 1024
#define BATCH   32
#define DIM     1024
#define NST     64
#define TBN     ((size_t)T_STEPS * BATCH * NST)   // 2M elements per projection

typedef __attribute__((ext_vector_type(8))) short bf16x8;
typedef __attribute__((ext_vector_type(4))) float f32x4;
typedef __attribute__((ext_vector_type(4))) unsigned short u16x4;

#define NLOG2E (-1.44269504088896340736f)
#define MFMA16(a, b, c) __builtin_amdgcn_mfma_f32_16x16x32_bf16(a, b, c, 0, 0, 0)

// Pre-split bf16 hi/lo planes of k and q (GEMM epilogue -> scan MFMA fragments).
__device__ unsigned short g_khi[TBN];
__device__ unsigned short g_klo[TBN];
__device__ unsigned short g_qhi[TBN];
__device__ unsigned short g_qlo[TBN];
// Pre-split bf16 hi/lo planes of the 4 weight matrices [proj][64][1024] (split_w prepass).
__device__ unsigned short g_whi[4 * 64 * 1024];
__device__ unsigned short g_wlo[4 * 64 * 1024];

__device__ __forceinline__ void gload16(const void* g, void* l)
{
    __builtin_amdgcn_global_load_lds(
        (const __attribute__((address_space(1))) unsigned int*)g,
        (__attribute__((address_space(3))) unsigned int*)l, 16, 0, 0);
}

// RNE hi/lo split: x = hi + lo, |lo| <= 2^-9|x|, residual ~2^-17 dropped.
__device__ __forceinline__ void split1_rne(float v, unsigned short& hi, unsigned short& lo)
{
    __hip_bfloat16 hb = __float2bfloat16(v);
    unsigned short hraw; __builtin_memcpy(&hraw, &hb, 2);
    float hf = __bfloat162float(hb);
    __hip_bfloat16 lb = __float2bfloat16(v - hf);
    unsigned short lraw; __builtin_memcpy(&lraw, &lb, 2);
    hi = hraw; lo = lraw;
}

__device__ __forceinline__ void cvt8(float4 v0, float4 v1, bf16x8& hi, bf16x8& lo)
{
    float f[8] = {v0.x, v0.y, v0.z, v0.w, v1.x, v1.y, v1.z, v1.w};
    bf16x8 h, l;
    #pragma unroll
    for (int i = 0; i < 8; i++) {
        unsigned short hr, lr;
        split1_rne(f[i], hr, lr);
        h[i] = (short)hr; l[i] = (short)lr;
    }
    hi = h; lo = l;
}

// ======================= Phase 0: one-shot W split prepass (~1MB, <5us) =======================
__global__ __launch_bounds__(256, 4)
void split_w(const float* __restrict__ Wk, const float* __restrict__ Wv,
             const float* __restrict__ Wq, const float* __restrict__ Wa)
{
    const int t = blockIdx.x * 256 + threadIdx.x;   // grid 64 -> 16384 threads
    const float* Ws[4] = {Wk, Wv, Wq, Wa};
    #pragma unroll
    for (int i = 0; i < 4; i++) {
        const int f4  = i * 16384 + t;              // float4 id 0..65535, coalesced per i
        const int idx = f4 * 4;                     // element index
        const int proj = idx >> 16;                 // 64*1024 elems per matrix
        const int rem  = idx & 65535;
        const float4 v = *(const float4*)(Ws[proj] + rem);
        const float f[4] = {v.x, v.y, v.z, v.w};
        u16x4 h, l;
        #pragma unroll
        for (int j = 0; j < 4; j++) {
            unsigned short hr, lr;
            split1_rne(f[j], hr, lr);
            h[j] = hr; l[j] = lr;
        }
        *(u16x4*)&g_whi[idx] = h;
        *(u16x4*)&g_wlo[idx] = l;
    }
}

// ======================= Phase 1: hi/lo bf16 MFMA GEMM, 128x128, 2 blocks/CU =======================
// r8 change: B operand staged directly from the pre-split bf16 W planes (split_w) ->
// all 4 B-side cvt8 calls deleted (~50% of inner-loop VALU). B LDS reads are 2-way
// aliased at worst (16 rows x 64B tile = exact 1KB cover) -> no swizzle needed.

__global__ __launch_bounds__(256, 2)
void proj_gemm_v3(const float* __restrict__ x,
                  const float* __restrict__ b_alpha,
                  float* __restrict__ ws)
{
    __shared__ float As[2][128][32];            // 32 KB
    __shared__ unsigned short Bh[2][128][32];   // 16 KB
    __shared__ unsigned short Bl[2][128][32];   // 16 KB  => 64 KB total

    const int tid  = threadIdx.x;
    const int lane = tid & 63;
    const int w    = tid >> 6;          // wave 0..3
    const int m0   = (blockIdx.x >> 1) * 128;
    const int nh   = blockIdx.x & 1;    // n-half: cols [128*nh, 128*nh+128)

    // A staging: LDS pos p of row r holds GLOBAL granule p ^ (r&7)  (fp32, swizzled)
    const int lrow  = lane >> 3;
    const int lgran = (lane & 7) ^ lrow;
    const float* ap[4];
    #pragma unroll
    for (int i = 0; i < 4; i++)
        ap[i] = x + (size_t)(m0 + 32*w + 8*i + lrow) * DIM + lgran * 4;

    // B staging (bf16 planes, linear): gload j covers 16 rows; lane L -> row L>>2, granule L&3
    const int proj = nh * 2 + (w >> 1);
    const int brow0 = (w & 1) * 32 + (lane >> 2);     // + 16*j
    const int bcol  = (lane & 3) * 8;                 // ushort elems
    const unsigned short* bsrc[2];
    #pragma unroll
    for (int j = 0; j < 2; j++)
        bsrc[j] = (const unsigned short*)g_whi
                + (size_t)proj * 65536 + (size_t)(brow0 + 16*j) * DIM + bcol;
    const size_t lo_off = (size_t)(g_wlo - g_whi);    // same layout

    auto stage = [&](int kb, int buf) {
        const int ko = kb * 32;
        #pragma unroll
        for (int i = 0; i < 4; i++)
            gload16(ap[i] + ko, &As[buf][32*w + 8*i][0]);
        #pragma unroll
        for (int j = 0; j < 2; j++) {
            gload16(bsrc[j] + ko,          &Bh[buf][32*w + 16*j][0]);
            gload16(bsrc[j] + lo_off + ko, &Bl[buf][32*w + 16*j][0]);
        }
    };

    const int fr = lane & 15;
    const int qi = lane >> 4;
    const int sx = fr & 7;
    const int mh  = w >> 1;             // m-half 0..1
    const int nqh = w & 1;              // n-quarter within block

    f32x4 acc[4][4];
    #pragma unroll
    for (int i = 0; i < 4; i++)
        #pragma unroll
        for (int j = 0; j < 4; j++)
            acc[i][j] = (f32x4)0.0f;

    stage(0, 0);
    __syncthreads();

    #pragma unroll 1
    for (int kb = 0; kb < 32; kb++) {
        const int buf = kb & 1;
        if (kb + 1 < 32) stage(kb + 1, buf ^ 1);

        bf16x8 ah[4], al[4], bh[4], bl[4];
        #pragma unroll
        for (int mt = 0; mt < 4; mt++) {
            const float* rp = &As[buf][mh*64 + mt*16 + fr][0];
            float4 v0 = *(const float4*)(rp + (((2*qi    ) ^ sx) * 4));
            float4 v1 = *(const float4*)(rp + (((2*qi + 1) ^ sx) * 4));
            cvt8(v0, v1, ah[mt], al[mt]);
        }
        #pragma unroll
        for (int nt = 0; nt < 4; nt++) {
            bh[nt] = *(const bf16x8*)&Bh[buf][nqh*64 + nt*16 + fr][qi * 8];
            bl[nt] = *(const bf16x8*)&Bl[buf][nqh*64 + nt*16 + fr][qi * 8];
        }
        #pragma unroll
        for (int mt = 0; mt < 4; mt++)
            #pragma unroll
            for (int nt = 0; nt < 4; nt++) {
                acc[mt][nt] = MFMA16(ah[mt], bh[nt], acc[mt][nt]);
                acc[mt][nt] = MFMA16(al[mt], bh[nt], acc[mt][nt]);
                acc[mt][nt] = MFMA16(ah[mt], bl[nt], acc[mt][nt]);
            }

        __syncthreads();
    }

    // epilogue: fp32 k/v/ax planes (ax pre-scaled by -log2e, b_alpha folded); bf16 hi/lo k,q
    const int nq = nh * 2 + nqh;        // projection this wave owns
    float* outb = ws + (size_t)nq * TBN;
    const int r0 = qi * 4;
    float bav[4];
    #pragma unroll
    for (int nt = 0; nt < 4; nt++)
        bav[nt] = (nq == 3) ? b_alpha[nt*16 + fr] : 0.0f;
    const float scl = (nq == 3) ? NLOG2E : 1.0f;
    #pragma unroll
    for (int mt = 0; mt < 4; mt++)
        #pragma unroll
        for (int nt = 0; nt < 4; nt++)
            #pragma unroll
            for (int r = 0; r < 4; r++) {
                const float val = (acc[mt][nt][r] + bav[nt]) * scl;
                const size_t idx = (size_t)(m0 + mh*64 + mt*16 + r0 + r) * NST + nt*16 + fr;
                if (nq != 2)
                    outb[idx] = val;
                if (nq == 0 || nq == 2) {
                    unsigned short hr, lr;
                    split1_rne(val, hr, lr);
                    if (nq == 0) { g_khi[idx] = hr; g_klo[idx] = lr; }
                    else         { g_qhi[idx] = hr; g_qlo[idx] = lr; }
                }
            }
}

// ======================= Phase 2: Gram-chunked scan + register operand burst =======================
// r5 structure (measured 132us). r8 change: the step loop's 4 LDS operands/step were NOT
// hoisted by the compiler (VGPR=52) -> ~120cy ds_read latency per step on the serial chain.
// Fix: fill kreg[16]/greg[16]/vv[16]/aa[16] register arrays in a burst before the chain
// (all compile-time indices); ~48 ds_reads retire under lgkm pipelining, chain runs reg-only.

#define SCH 16
#define NCH (T_STEPS / SCH)

__global__ __launch_bounds__(256, 2)
void scan_gram2(const float* __restrict__ ws,
                const float* __restrict__ S0,
                const float* __restrict__ d_alpha,
                float* __restrict__ out)
{
    const float* kb_ = ws;             // k fp32 (for S update)
    const float* vb_ = ws + TBN;       // v fp32
    const float* ab_ = ws + 3 * TBN;   // pre-scaled -log2e*(ax+b_alpha)

    __shared__ float k_st[2][SCH][64];            // 8 KB
    __shared__ float va  [2][SCH][16];            // 2 KB
    __shared__ float GG  [2][SCH][16][2];         // 4 KB  [s][j][{G,GQ}]
    __shared__ unsigned short KH[2][SCH][64];     // 4 KB each, 16 KB total
    __shared__ unsigned short KL[2][SCH][64];
    __shared__ unsigned short QH[2][SCH][64];
    __shared__ unsigned short QL[2][SCH][64];
    __shared__ float S_pvt[4][64];                // 1 KB

    const int tid  = threadIdx.x;
    const int lane = tid & 63;
    const int w    = tid >> 6;          // wave = row-in-group 0..3
    const int bid  = blockIdx.x;
    // XCD swizzle: all 16 row-groups of a batch share an XCD class
    const int b    = (bid & 7) * 4 + ((bid >> 3) & 3);
    const int rg   = bid >> 5;
    const int row  = rg * 4 + w;
    const int fr   = lane & 15;
    const int qi   = lane >> 4;

    const size_t stp = (size_t)BATCH * NST;   // 2048

    float S = S0[((size_t)b * NST + row) * NST + lane];   // one column per lane
    const float da_s = d_alpha[row] * NLOG2E;

    // ---- staging sources ----
    const float* ksrc = kb_ + (size_t)(4*w + qi) * stp + (size_t)b * NST + fr * 4;
    const float* vsrc = ((lane & 1) ? ab_ : vb_)
                      + (size_t)(lane >> 2) * stp + (size_t)b * NST + rg * 4;

    const unsigned short* pl_g = (w == 0) ? g_khi : (w == 1) ? g_klo
                               : (w == 2) ? g_qhi : g_qlo;
    const int prow  = lane >> 3;
    const int pgran = (lane & 7) ^ prow;          // swizzled source 16B-slot
    const unsigned short* psrc0 = pl_g + ((size_t)prow       * stp + (size_t)b * NST + pgran * 8);
    const unsigned short* psrc1 = pl_g + ((size_t)(8 + prow) * stp + (size_t)b * NST + pgran * 8);

    auto stage = [&](int ch, int buf) {
        const size_t koff = (size_t)ch * SCH * stp;
        gload16(ksrc + koff, &k_st[buf][4*w][0]);
        if (w == 0)
            gload16(vsrc + koff, &va[buf][0][0]);
        unsigned short* pdst = (w == 0) ? &KH[buf][0][0] : (w == 1) ? &KL[buf][0][0]
                             : (w == 2) ? &QH[buf][0][0] : &QL[buf][0][0];
        gload16(psrc0 + koff, pdst);
        gload16(psrc1 + koff, pdst + 8 * 64);
    };

    // read-side swizzle cols (ushort units)
    const int c1 = (qi ^ (fr & 7)) * 8;
    const int c2 = c1 ^ 32;

    stage(0, 0);
    __syncthreads();

    float* op = out + (size_t)b * NST + row;
    float hv = 0.0f;

    #pragma unroll 1
    for (int ch = 0; ch < NCH; ch++) {
        const int buf = ch & 1;

        // ---- frag reads from swizzled LDS (bank-free b128) ----
        const bf16x8 Kh0 = *(const bf16x8*)&KH[buf][fr][c1];
        const bf16x8 Kh1 = *(const bf16x8*)&KH[buf][fr][c2];
        const bf16x8 Kl0 = *(const bf16x8*)&KL[buf][fr][c1];
        const bf16x8 Kl1 = *(const bf16x8*)&KL[buf][fr][c2];
        const bf16x8 Qh0 = *(const bf16x8*)&QH[buf][fr][c1];
        const bf16x8 Qh1 = *(const bf16x8*)&QH[buf][fr][c2];
        const bf16x8 Ql0 = *(const bf16x8*)&QL[buf][fr][c1];
        const bf16x8 Ql1 = *(const bf16x8*)&QL[buf][fr][c2];

        // ---- S broadcast + hi/lo split (RNE) ----
        S_pvt[w][lane] = S;
        bf16x8 Sh0, Sl0, Sh1, Sl1;
        {
            float4 s0 = *(const float4*)&S_pvt[w][qi * 8];
            float4 s1 = *(const float4*)&S_pvt[w][qi * 8 + 4];
            cvt8(s0, s1, Sh0, Sl0);
            float4 s2 = *(const float4*)&S_pvt[w][32 + qi * 8];
            float4 s3 = *(const float4*)&S_pvt[w][32 + qi * 8 + 4];
            cvt8(s2, s3, Sh1, Sl1);
        }

        // ---- R0 = S.K^T, H0 = S.Q^T (all waves; hi/lo 3-term) ----
        f32x4 aR0 = (f32x4)0.0f, aR1 = (f32x4)0.0f;
        f32x4 aH0 = (f32x4)0.0f, aH1 = (f32x4)0.0f;
        aR0 = MFMA16(Sh0, Kh0, aR0); aR0 = MFMA16(Sh0, Kl0, aR0); aR0 = MFMA16(Sl0, Kh0, aR0);
        aR1 = MFMA16(Sh1, Kh1, aR1); aR1 = MFMA16(Sh1, Kl1, aR1); aR1 = MFMA16(Sl1, Kh1, aR1);
        aH0 = MFMA16(Sh0, Qh0, aH0); aH0 = MFMA16(Sh0, Ql0, aH0); aH0 = MFMA16(Sl0, Qh0, aH0);
        aH1 = MFMA16(Sh1, Qh1, aH1); aH1 = MFMA16(Sh1, Ql1, aH1); aH1 = MFMA16(Sl1, Qh1, aH1);
        float R = aR0[0] + aR1[0];
        float H = aH0[0] + aH1[0];

        // ---- Gram tables for THIS chunk, split across waves ----
        if (w == 0) {
            f32x4 aG = (f32x4)0.0f;
            aG = MFMA16(Kh0, Kh0, aG); aG = MFMA16(Kh0, Kl0, aG); aG = MFMA16(Kl0, Kh0, aG);
            aG = MFMA16(Kh1, Kh1, aG); aG = MFMA16(Kh1, Kl1, aG); aG = MFMA16(Kl1, Kh1, aG);
            #pragma unroll
            for (int r = 0; r < 4; r++) GG[buf][qi*4 + r][fr][0] = aG[r];
        } else if (w == 1) {
            f32x4 aQ = (f32x4)0.0f;
            aQ = MFMA16(Kh0, Qh0, aQ); aQ = MFMA16(Kh0, Ql0, aQ); aQ = MFMA16(Kl0, Qh0, aQ);
            aQ = MFMA16(Kh1, Qh1, aQ); aQ = MFMA16(Kh1, Ql1, aQ); aQ = MFMA16(Kl1, Qh1, aQ);
            #pragma unroll
            for (int r = 0; r < 4; r++) GG[buf][qi*4 + r][fr][1] = aQ[r];
        }

        __syncthreads();   // A: GG[buf] visible; only lgkm outstanding -> cheap drain

        if (ch + 1 < NCH) stage(ch + 1, buf ^ 1);   // loads fly under the step loop

        // ---- operand burst into registers (compile-time indices -> VGPRs) ----
        float  kreg[SCH], vvr[SCH], aar[SCH];
        float2 greg[SCH];
        #pragma unroll
        for (int s = 0; s < SCH; s++) {
            kreg[s] = k_st[buf][s][lane];
            greg[s] = *(const float2*)&GG[buf][s][fr][0];
            vvr[s]  = va[buf][s][w];
            aar[s]  = va[buf][s][4 + w];
        }

        // ---- 16 steps, register-only: chain = readlane -> fma -> exp2 -> rcp ----
        #pragma unroll
        for (int s = 0; s < SCH; s++) {
            const float ret   = __int_as_float(
                __builtin_amdgcn_readlane(__float_as_int(R), s));
            const float z     = fmaf(da_s, ret, aar[s]);      // pre-scaled by -log2e
            const float e     = __builtin_amdgcn_exp2f(z);
            const float alpha = __builtin_amdgcn_rcpf(1.0f + e);
            const float bt    = (1.0f - alpha) * vvr[s];

            R = fmaf(alpha, R, bt * greg[s].x);
            H = fmaf(alpha, H, bt * greg[s].y);
            S = fmaf(alpha, S, bt * kreg[s]);

            hv = (lane == s) ? H : hv;            // h_t lands in lane s
        }

        // ---- chunk outputs: o = h * silu(h) ----
        {
            const float sg = __builtin_amdgcn_rcpf(1.0f + __builtin_amdgcn_exp2f(hv * NLOG2E));
            const float o  = hv * hv * sg;
            if (lane < SCH)
                op[(size_t)(ch * SCH + lane) * stp] = o;
        }

        __syncthreads();   // B: step-loop LDS reads done; next-chunk stage loads drained
    }

    // S_final: one column per lane, coalesced
    out[TBN + ((size_t)b * NST + row) * NST + lane] = S;
}

// ======================= launch =======================

extern "C" void kernel_launch(void* const* d_in, const int* in_sizes, int n_in,
                              void* d_out, int out_size, void* d_ws, size_t ws_size,
                              hipStream_t stream)
{
    const float* x  = (const float*)d_in[0];
    const float* S0 = (const float*)d_in[1];
    const float* Wk = (const float*)d_in[2];
    const float* Wv = (const float*)d_in[3];
    const float* Wq = (const float*)d_in[4];
    const float* Wa = (const float*)d_in[5];
    const float* da = (const float*)d_in[6];
    const float* ba = (const float*)d_in[7];
    float* out = (float*)d_out;
    float* ws  = (float*)d_ws;   // 4 x [T,B,N] fp32 = 32 MiB

    split_w<<<dim3(64), 256, 0, stream>>>(Wk, Wv, Wq, Wa);

    proj_gemm_v3<<<dim3((T_STEPS * BATCH) / 128 * 2), 256, 0, stream>>>(x, ba, ws);

    scan_gram2<<<dim3(BATCH * 16), 256, 0, stream>>>(ws, S0, da, out);
}